// Round 16
// baseline (466.114 us; speedup 1.0000x reference)
//
#include <hip/hip_runtime.h>

// MixingAttention on MI355X (gfx950) — ROUND 16.
// r15 post-mortem: counted-vmcnt dbuf = -59us on QKV/out/attn (keep);
// gemm_f32a = latency-bound regression (170us @ 11% MFMA) -> reverted to
// cast pass + bf16 gemm_glds for proj (now with counted vmcnt too).
// Attn: + s_setprio(1) around MFMA clusters (T5).

using s16x8 = __attribute__((ext_vector_type(8))) short;   // 8 bf16
using f32x4 = __attribute__((ext_vector_type(4))) float;   // 4 f32 acc
typedef __attribute__((ext_vector_type(2))) unsigned u32x2;

#define NTOK 144
#define NHEADS 16
#define CDIM 512
#define TROWS 9216
#define SROWS 36864
#define TOTROWS 46080
#define NWIN 320
#define NCLS 20

__device__ __forceinline__ unsigned short f2bf(float f) {
  unsigned u = __float_as_uint(f);
  u += 0x7fffu + ((u >> 16) & 1u);     // RNE
  return (unsigned short)(u >> 16);
}
__device__ __forceinline__ float bf2f(unsigned short u) {
  return __uint_as_float(((unsigned)u) << 16);
}
__device__ __forceinline__ s16x8 mk8(unsigned a, unsigned b, unsigned c, unsigned d) {
  union { unsigned u[4]; s16x8 v; } x;
  x.u[0] = a; x.u[1] = b; x.u[2] = c; x.u[3] = d;
  return x.v;
}

// async global->LDS, 16B per lane; lds base wave-uniform.
__device__ __forceinline__ void gld16(const void* g, void* l) {
  __builtin_amdgcn_global_load_lds(
      (const __attribute__((address_space(1))) unsigned int*)g,
      (__attribute__((address_space(3))) unsigned int*)l, 16, 0, 0);
}

// ---------------- prep kernels ----------------

__global__ void transpose_cast(const float* __restrict__ w,
                               unsigned short* __restrict__ wT, int Kd, int Nd,
                               int nScale, float s) {
  int i = blockIdx.x * 256 + threadIdx.x;
  if (i >= Kd * Nd) return;
  int n = i / Kd, k = i % Kd;
  float v = w[(size_t)k * Nd + n];
  if (n < nScale) v *= s;
  wT[i] = f2bf(v);
}

__global__ void scale_bias(const float* __restrict__ in, float* __restrict__ out) {
  int i = blockIdx.x * 256 + threadIdx.x;
  if (i >= 1536) return;
  out[i] = in[i] * (i < 512 ? 0.17677669529663687f : 1.0f);
}

// f32 -> bf16 bulk cast, 8 elems/thread
__global__ __launch_bounds__(256) void cast_bf16(const float* __restrict__ in,
                                                 unsigned short* __restrict__ out, int n8) {
  int i = blockIdx.x * 256 + threadIdx.x;
  if (i >= n8) return;
  const float4* p = (const float4*)in + (size_t)i * 2;
  float4 f0 = p[0], f1 = p[1];
  s16x8 o;
  o[0] = (short)f2bf(f0.x); o[1] = (short)f2bf(f0.y);
  o[2] = (short)f2bf(f0.z); o[3] = (short)f2bf(f0.w);
  o[4] = (short)f2bf(f1.x); o[5] = (short)f2bf(f1.y);
  o[6] = (short)f2bf(f1.z); o[7] = (short)f2bf(f1.w);
  *(s16x8*)&out[(size_t)i * 8] = o;
}

__global__ void build_cmb(const float* __restrict__ rpb, const float* __restrict__ m0,
                          const float* __restrict__ m1, unsigned short* __restrict__ cmb) {
  int i = blockIdx.x * 256 + threadIdx.x;
  if (i >= NCLS * NHEADS * NTOK * NTOK) return;
  int cls = i / (NHEADS * NTOK * NTOK);
  int rem = i % (NHEADS * NTOK * NTOK);
  int h = rem / (NTOK * NTOK);
  int ij = rem % (NTOK * NTOK);
  int qi = ij / NTOK, kj = ij % NTOK;
  int dh = qi / 12 - kj / 12 + 11;
  int dw = qi % 12 - kj % 12 + 11;
  float bias = rpb[(dh * 23 + dw) * NHEADS + h];
  float mv = (cls < 4) ? m1[(size_t)cls * NTOK * NTOK + ij]
                       : m0[(size_t)(cls - 4) * NTOK * NTOK + ij];
  cmb[i] = f2bf(bias + mv);
}

// ---------------- bf16 GEMM: BK=64, swizzle, dbuf, counted vmcnt ----------
// EPI 0: +bias, bf16.  EPI 2: +bias, f32.
template<int EPI>
__global__ __launch_bounds__(256) void gemm_glds(
    const unsigned short* __restrict__ Ab,
    const unsigned short* __restrict__ BTt, const unsigned short* __restrict__ BTs,
    const float* __restrict__ biast, const float* __restrict__ biass,
    void* __restrict__ Cout, int M, int N, int K)
{
  __shared__ short As[2][128 * 64];
  __shared__ short Bs[2][128 * 64];
  const int t = threadIdx.x;
  const int lane = t & 63, wv = t >> 6, lg = lane >> 4, lc = lane & 15;

  const int id = blockIdx.x + gridDim.x * blockIdx.y;
  const int chunk = (gridDim.x * gridDim.y) >> 3;
  const int lid = (id & 7) * chunk + (id >> 3);
  const int bn = (lid % gridDim.x) * 128, bm = (lid / gridDim.x) * 128;

  const bool isT = bm < TROWS;
  const unsigned short* BT = isT ? BTt : BTs;
  const float* bias = isT ? biast : biass;

  const int srow = 32 * wv + (lane >> 3);
  const int scol = ((lane & 7) ^ ((lane >> 3) & 7)) * 8;
  const unsigned short* aSrc = Ab + (size_t)(bm + srow) * K + scol;
  const unsigned short* bSrc = BT + (size_t)(bn + srow) * K + scol;
  const size_t rowK8 = (size_t)8 * K;

  f32x4 acc[2][8] = {};

  auto STAGE = [&](int b, int kt) {
#pragma unroll
    for (int i = 0; i < 4; i++) {
      gld16(aSrc + kt + i * rowK8, &As[b][(wv * 4 + i) * 512]);
      gld16(bSrc + kt + i * rowK8, &Bs[b][(wv * 4 + i) * 512]);
    }
  };
  auto COMPUTE = [&](int b) {
#pragma unroll
    for (int kk = 0; kk < 2; kk++) {
      const int csw = 8 * ((4 * kk + lg) ^ (lc & 7));
      const int r0 = wv * 32 + lc, r1 = r0 + 16;
      s16x8 a0 = *(const s16x8*)&As[b][r0 * 64 + csw];
      s16x8 a1 = *(const s16x8*)&As[b][r1 * 64 + csw];
#pragma unroll
      for (int nt = 0; nt < 8; nt++) {
        s16x8 bfr = *(const s16x8*)&Bs[b][(nt * 16 + lc) * 64 + csw];
        acc[0][nt] = __builtin_amdgcn_mfma_f32_16x16x32_bf16(a0, bfr, acc[0][nt], 0, 0, 0);
        acc[1][nt] = __builtin_amdgcn_mfma_f32_16x16x32_bf16(a1, bfr, acc[1][nt], 0, 0, 0);
      }
    }
  };

  STAGE(0, 0);
  int cur = 0;
  for (int kt = 64; kt < K; kt += 64) {
    STAGE(cur ^ 1, kt);                       // 8 loads in flight (next tile)
    asm volatile("s_waitcnt vmcnt(8)" ::: "memory");   // prev tile retired
    __builtin_amdgcn_s_barrier();             // all waves' stages visible
    __builtin_amdgcn_sched_barrier(0);
    COMPUTE(cur);
    __builtin_amdgcn_s_barrier();             // reads done before buf reuse
    cur ^= 1;
  }
  asm volatile("s_waitcnt vmcnt(0)" ::: "memory");
  __builtin_amdgcn_s_barrier();
  __builtin_amdgcn_sched_barrier(0);
  COMPUTE(cur);

#pragma unroll
  for (int mt = 0; mt < 2; mt++) {
    const int rbase = bm + wv * 32 + mt * 16 + lg * 4;
#pragma unroll
    for (int nt = 0; nt < 8; nt++) {
      const int cg = bn + nt * 16 + lc;
#pragma unroll
      for (int r = 0; r < 4; r++) {
        const int rg = rbase + r;
        float val = acc[mt][nt][r] + bias[cg];
        if (EPI == 2) ((float*)Cout)[(size_t)rg * N + cg] = val;
        else ((unsigned short*)Cout)[(size_t)rg * N + cg] = f2bf(val);
      }
    }
  }
}

// ---------------- LayerNorm, in place (wave per row) ----------------
__global__ __launch_bounds__(256) void ln_kernel(
    unsigned short* __restrict__ xa,
    const float* __restrict__ g_pt, const float* __restrict__ be_pt,
    const float* __restrict__ g_ps, const float* __restrict__ be_ps)
{
  const int row = blockIdx.x * 4 + (threadIdx.x >> 6);
  const int lane = threadIdx.x & 63;
  const bool isT = row < TROWS;
  const float* gg = isT ? g_pt : g_ps;
  const float* be = isT ? be_pt : be_ps;
  unsigned short* p = xa + (size_t)row * CDIM;
  const int c0 = lane * 8;

  s16x8 v8 = *(const s16x8*)&p[c0];
  float f[8];
  float s = 0.f, s2 = 0.f;
#pragma unroll
  for (int i = 0; i < 8; i++) {
    float xv = bf2f((unsigned short)v8[i]);
    f[i] = xv; s += xv; s2 += xv * xv;
  }
#pragma unroll
  for (int d = 1; d < 64; d <<= 1) { s += __shfl_xor(s, d); s2 += __shfl_xor(s2, d); }
  float mu = s * (1.f / CDIM);
  float var = s2 * (1.f / CDIM) - mu * mu;
  float rs = rsqrtf(var + 1e-5f);

  float4 g0 = *(const float4*)&gg[c0], g1 = *(const float4*)&gg[c0 + 4];
  float4 e0 = *(const float4*)&be[c0], e1 = *(const float4*)&be[c0 + 4];
  float gv[8] = {g0.x, g0.y, g0.z, g0.w, g1.x, g1.y, g1.z, g1.w};
  float ev[8] = {e0.x, e0.y, e0.z, e0.w, e1.x, e1.y, e1.z, e1.w};
  s16x8 o;
#pragma unroll
  for (int i = 0; i < 8; i++)
    o[i] = (short)f2bf((f[i] - mu) * rs * gv[i] + ev[i]);
  *(s16x8*)&p[c0] = o;
}

// ---------------- fused attention (+ setprio around MFMA) ----------------
__global__ __launch_bounds__(576) void attn_kernel(
    const unsigned short* __restrict__ qkv, const unsigned short* __restrict__ cmb,
    unsigned short* __restrict__ outp)
{
  __shared__ short VT[32 * 168];
  const int nb = NWIN * NHEADS;
  const int lid = (blockIdx.x & 7) * (nb >> 3) + (blockIdx.x >> 3);
  const int w = lid >> 4, h = lid & 15;
  const int t = threadIdx.x;
  const unsigned short* qb = qkv + (size_t)w * NTOK * 1536;
  const int hq = h * 32;

  {
    const int n = t >> 2, d0 = (t & 3) * 8;
    s16x8 vv = *(const s16x8*)&qb[(size_t)n * 1536 + 1024 + hq + d0];
#pragma unroll
    for (int i = 0; i < 8; i++) VT[(d0 + i) * 168 + n] = vv[i];
  }
  if (t < 512) VT[(t >> 4) * 168 + 144 + (t & 15)] = 0;

  const int lane = t & 63, wv = t >> 6, lg = lane >> 4, lc = lane & 15;
  const int q = wv * 16 + lc;
  const f32x4 zero = {0.f, 0.f, 0.f, 0.f};

  const s16x8 qf = *(const s16x8*)&qb[(size_t)q * 1536 + hq + lg * 8];

  const int cls = (w < 64) ? (w & 3) : 4 + ((w - 64) & 15);
  const unsigned short* cm =
      cmb + ((size_t)cls * NHEADS + h) * (NTOK * NTOK) + (size_t)q * NTOK;
  uint2 cmr[9];
#pragma unroll
  for (int nt = 0; nt < 9; nt++)
    cmr[nt] = *(const uint2*)&cm[nt * 16 + lg * 4];

  f32x4 accS[9];
  __builtin_amdgcn_s_setprio(1);
#pragma unroll
  for (int nt = 0; nt < 9; nt++) {
    s16x8 kf = *(const s16x8*)&qb[(size_t)(nt * 16 + lc) * 1536 + 512 + hq + lg * 8];
    accS[nt] = __builtin_amdgcn_mfma_f32_16x16x32_bf16(kf, qf, zero, 0, 0, 0);
  }
  __builtin_amdgcn_s_setprio(0);

  float mx = -1e30f;
#pragma unroll
  for (int nt = 0; nt < 9; nt++) {
    accS[nt][0] += bf2f((unsigned short)(cmr[nt].x & 0xffff));
    accS[nt][1] += bf2f((unsigned short)(cmr[nt].x >> 16));
    accS[nt][2] += bf2f((unsigned short)(cmr[nt].y & 0xffff));
    accS[nt][3] += bf2f((unsigned short)(cmr[nt].y >> 16));
#pragma unroll
    for (int r = 0; r < 4; r++) mx = fmaxf(mx, accS[nt][r]);
  }
  mx = fmaxf(mx, __shfl_xor(mx, 16));
  mx = fmaxf(mx, __shfl_xor(mx, 32));

  float sum = 0.f;
#pragma unroll
  for (int nt = 0; nt < 9; nt++)
#pragma unroll
    for (int r = 0; r < 4; r++) {
      float e = __expf(accS[nt][r] - mx);
      accS[nt][r] = e;
      sum += e;
    }
  sum += __shfl_xor(sum, 16);
  sum += __shfl_xor(sum, 32);
  const float inv = 1.f / sum;

  unsigned pk0[9], pk1[9];
#pragma unroll
  for (int nt = 0; nt < 9; nt++) {
    pk0[nt] = (unsigned)f2bf(accS[nt][0]) | ((unsigned)f2bf(accS[nt][1]) << 16);
    pk1[nt] = (unsigned)f2bf(accS[nt][2]) | ((unsigned)f2bf(accS[nt][3]) << 16);
  }

  __syncthreads();

  __builtin_amdgcn_s_setprio(1);
#pragma unroll
  for (int dt = 0; dt < 2; dt++) {
    const short* vbase = &VT[(dt * 16 + lc) * 168];
    f32x4 accO = zero;
#pragma unroll
    for (int kk = 0; kk < 4; kk++) {
      u32x2 A0 = *(const u32x2*)&vbase[32 * kk + lg * 4];
      u32x2 A1 = *(const u32x2*)&vbase[32 * kk + 16 + lg * 4];
      s16x8 a = mk8(A0[0], A0[1], A1[0], A1[1]);
      s16x8 b = mk8(pk0[2 * kk], pk1[2 * kk], pk0[2 * kk + 1], pk1[2 * kk + 1]);
      accO = __builtin_amdgcn_mfma_f32_16x16x32_bf16(a, b, accO, 0, 0, 0);
    }
    {
      u32x2 A0 = *(const u32x2*)&vbase[128 + lg * 4];
      s16x8 a = mk8(A0[0], A0[1], 0u, 0u);
      s16x8 b = mk8(pk0[8], pk1[8], 0u, 0u);
      accO = __builtin_amdgcn_mfma_f32_16x16x32_bf16(a, b, accO, 0, 0, 0);
    }
    unsigned o0 = (unsigned)f2bf(accO[0] * inv) | ((unsigned)f2bf(accO[1] * inv) << 16);
    unsigned o1 = (unsigned)f2bf(accO[2] * inv) | ((unsigned)f2bf(accO[3] * inv) << 16);
    uint2 st; st.x = o0; st.y = o1;
    *(uint2*)&outp[(size_t)(w * NTOK + q) * CDIM + hq + dt * 16 + lg * 4] = st;
  }
  __builtin_amdgcn_s_setprio(0);
}

// ---------------- launch ----------------
extern "C" void kernel_launch(void* const* d_in, const int* in_sizes, int n_in,
                              void* d_out, int out_size, void* d_ws, size_t ws_size,
                              hipStream_t stream)
{
  const float* x     = (const float*)d_in[0];
  const float* tpl   = (const float*)d_in[1];
  const float* mask0 = (const float*)d_in[2];
  const float* mask1 = (const float*)d_in[3];
  const float* rpb   = (const float*)d_in[8];
  const float* w_ps  = (const float*)d_in[9];
  const float* b_ps  = (const float*)d_in[10];
  const float* g_ps  = (const float*)d_in[11];
  const float* be_ps = (const float*)d_in[12];
  const float* w_pt  = (const float*)d_in[13];
  const float* b_pt  = (const float*)d_in[14];
  const float* g_pt  = (const float*)d_in[15];
  const float* be_pt = (const float*)d_in[16];
  const float* w_qkv = (const float*)d_in[17];
  const float* b_qkv = (const float*)d_in[18];
  const float* w_tr  = (const float*)d_in[19];
  const float* b_tr  = (const float*)d_in[20];
  const float* w_sr  = (const float*)d_in[21];
  const float* b_sr  = (const float*)d_in[22];

  char* ws = (char*)d_ws;
  unsigned short* wpsT  = (unsigned short*)(ws + 0x0000000);
  unsigned short* wptT  = (unsigned short*)(ws + 0x0100000);
  unsigned short* wqkvT = (unsigned short*)(ws + 0x0200000);
  unsigned short* wtrT  = (unsigned short*)(ws + 0x0380000);
  unsigned short* wsrT  = (unsigned short*)(ws + 0x0480000);
  unsigned short* cmb   = (unsigned short*)(ws + 0x0580000);
  float* bqS            = (float*)(ws + 0x12F0000);
  unsigned short* xa    = (unsigned short*)(ws + 0x1300000);
  unsigned short* Sa    = (unsigned short*)(ws + 0x4000000);   // cast-A (union
  unsigned short* qkvF  = (unsigned short*)(ws + 0x4000000);   //  w/ qkv)
  float* outb           = (float*)d_out;

  transpose_cast<<<2048, 256, 0, stream>>>(w_ps, wpsT, 1024, 512, 0, 1.f);
  transpose_cast<<<2048, 256, 0, stream>>>(w_pt, wptT, 1024, 512, 0, 1.f);
  transpose_cast<<<3072, 256, 0, stream>>>(w_qkv, wqkvT, 512, 1536,
                                           512, 0.17677669529663687f);
  transpose_cast<<<2048, 256, 0, stream>>>(w_tr, wtrT, 512, 1024, 0, 1.f);
  transpose_cast<<<2048, 256, 0, stream>>>(w_sr, wsrT, 512, 1024, 0, 1.f);
  scale_bias<<<6, 256, 0, stream>>>(b_qkv, bqS);
  build_cmb<<<(NCLS * NHEADS * NTOK * NTOK + 255) / 256, 256, 0, stream>>>(rpb, mask0, mask1, cmb);

  // cast inputs to bf16: tpl -> Sa[0:9216), x -> Sa[9216:46080)
  cast_bf16<<<(TROWS * 1024 / 8 + 255) / 256, 256, 0, stream>>>(tpl, Sa, TROWS * 1024 / 8);
  cast_bf16<<<(SROWS * 1024 / 8 + 255) / 256, 256, 0, stream>>>(
      x, Sa + (size_t)TROWS * 1024, SROWS * 1024 / 8);

  // projection GEMM -> xa bf16
  gemm_glds<0><<<dim3(4, 360), 256, 0, stream>>>(Sa, wptT, wpsT, b_pt, b_ps,
                                                 xa, TOTROWS, CDIM, 1024);
  // LayerNorm in place on xa
  ln_kernel<<<TOTROWS / 4, 256, 0, stream>>>(xa, g_pt, be_pt, g_ps, be_ps);

  // QKV GEMM (Q-scale folded) -> qkvF (overwrites dead Sa)
  gemm_glds<0><<<dim3(12, 360), 256, 0, stream>>>(xa, wqkvT, wqkvT, bqS, bqS,
                                                  qkvF, TOTROWS, 1536, CDIM);
  // fused attention -> xa
  attn_kernel<<<NWIN * NHEADS, 576, 0, stream>>>(qkvF, cmb, xa);

  // output GEMM -> d_out f32
  gemm_glds<2><<<dim3(8, 360), 256, 0, stream>>>(xa, wtrT, wsrT, b_tr, b_sr,
                                                 outb, TOTROWS, 1024, CDIM);
}

// Round 17
// 453.145 us; speedup vs baseline: 1.0286x; 1.0286x over previous
//
#include <hip/hip_runtime.h>

// MixingAttention on MI355X (gfx950) — ROUND 17.
// GEMM scaled to 256x256 tile (8 waves, BK=64, dbuf, counted vmcnt(8),
// XOR swizzle, XCD chunking) — compute phase per K-step now ~2x HBM latency
// cover. 128KB dynamic LDS via hipFuncSetAttribute. Same staging/compute/
// barrier pattern as the verified r15/16 structure.

using s16x8 = __attribute__((ext_vector_type(8))) short;   // 8 bf16
using f32x4 = __attribute__((ext_vector_type(4))) float;   // 4 f32 acc
typedef __attribute__((ext_vector_type(2))) unsigned u32x2;

#define NTOK 144
#define NHEADS 16
#define CDIM 512
#define TROWS 9216
#define SROWS 36864
#define TOTROWS 46080
#define NWIN 320
#define NCLS 20

__device__ __forceinline__ unsigned short f2bf(float f) {
  unsigned u = __float_as_uint(f);
  u += 0x7fffu + ((u >> 16) & 1u);     // RNE
  return (unsigned short)(u >> 16);
}
__device__ __forceinline__ float bf2f(unsigned short u) {
  return __uint_as_float(((unsigned)u) << 16);
}
__device__ __forceinline__ s16x8 mk8(unsigned a, unsigned b, unsigned c, unsigned d) {
  union { unsigned u[4]; s16x8 v; } x;
  x.u[0] = a; x.u[1] = b; x.u[2] = c; x.u[3] = d;
  return x.v;
}

// async global->LDS, 16B per lane; lds base wave-uniform.
__device__ __forceinline__ void gld16(const void* g, void* l) {
  __builtin_amdgcn_global_load_lds(
      (const __attribute__((address_space(1))) unsigned int*)g,
      (__attribute__((address_space(3))) unsigned int*)l, 16, 0, 0);
}

// ---------------- prep kernels ----------------

__global__ void transpose_cast(const float* __restrict__ w,
                               unsigned short* __restrict__ wT, int Kd, int Nd,
                               int nScale, float s) {
  int i = blockIdx.x * 256 + threadIdx.x;
  if (i >= Kd * Nd) return;
  int n = i / Kd, k = i % Kd;
  float v = w[(size_t)k * Nd + n];
  if (n < nScale) v *= s;
  wT[i] = f2bf(v);
}

__global__ void scale_bias(const float* __restrict__ in, float* __restrict__ out) {
  int i = blockIdx.x * 256 + threadIdx.x;
  if (i >= 1536) return;
  out[i] = in[i] * (i < 512 ? 0.17677669529663687f : 1.0f);
}

__global__ __launch_bounds__(256) void cast_bf16(const float* __restrict__ in,
                                                 unsigned short* __restrict__ out, int n8) {
  int i = blockIdx.x * 256 + threadIdx.x;
  if (i >= n8) return;
  const float4* p = (const float4*)in + (size_t)i * 2;
  float4 f0 = p[0], f1 = p[1];
  s16x8 o;
  o[0] = (short)f2bf(f0.x); o[1] = (short)f2bf(f0.y);
  o[2] = (short)f2bf(f0.z); o[3] = (short)f2bf(f0.w);
  o[4] = (short)f2bf(f1.x); o[5] = (short)f2bf(f1.y);
  o[6] = (short)f2bf(f1.z); o[7] = (short)f2bf(f1.w);
  *(s16x8*)&out[(size_t)i * 8] = o;
}

__global__ void build_cmb(const float* __restrict__ rpb, const float* __restrict__ m0,
                          const float* __restrict__ m1, unsigned short* __restrict__ cmb) {
  int i = blockIdx.x * 256 + threadIdx.x;
  if (i >= NCLS * NHEADS * NTOK * NTOK) return;
  int cls = i / (NHEADS * NTOK * NTOK);
  int rem = i % (NHEADS * NTOK * NTOK);
  int h = rem / (NTOK * NTOK);
  int ij = rem % (NTOK * NTOK);
  int qi = ij / NTOK, kj = ij % NTOK;
  int dh = qi / 12 - kj / 12 + 11;
  int dw = qi % 12 - kj % 12 + 11;
  float bias = rpb[(dh * 23 + dw) * NHEADS + h];
  float mv = (cls < 4) ? m1[(size_t)cls * NTOK * NTOK + ij]
                       : m0[(size_t)(cls - 4) * NTOK * NTOK + ij];
  cmb[i] = f2bf(bias + mv);
}

// ---------------- 256x256 MFMA GEMM: BK=64, 8 waves, dbuf, vmcnt(8) --------
// Wave (wr,wc) = (wv>>2, wv&3) owns output rows [wr*128,+128) x cols [wc*64,+64).
// Dynamic LDS 128KB: A[2][256*64] shorts then B[2][256*64].
// LDS slot (row, grp p) holds global col-group p ^ (row&7).
// EPI 0: +bias, bf16.  EPI 2: +bias, f32.
template<int EPI>
__global__ __launch_bounds__(512, 2) void gemm256(
    const unsigned short* __restrict__ Ab,
    const unsigned short* __restrict__ BTt, const unsigned short* __restrict__ BTs,
    const float* __restrict__ biast, const float* __restrict__ biass,
    void* __restrict__ Cout, int M, int N, int K)
{
  extern __shared__ short smem[];          // 128KB
  const int t = threadIdx.x;
  const int lane = t & 63, wv = t >> 6, lg = lane >> 4, lc = lane & 15;
  const int wr = wv >> 2, wc = wv & 3;

  const int id = blockIdx.x + gridDim.x * blockIdx.y;
  const int chunk = (gridDim.x * gridDim.y) >> 3;
  const int lid = (id & 7) * chunk + (id >> 3);
  const int bn = (lid % gridDim.x) * 256, bm = (lid / gridDim.x) * 256;

  const bool isT = bm < TROWS;
  const unsigned short* BT = isT ? BTt : BTs;
  const float* bias = isT ? biast : biass;

  // staging: wave wv, instr i (0..3) covers rows wv*32 + i*8 + (l>>3);
  // pre-swizzled source col-group (l&7)^((l>>3)&7); LDS dest linear.
  const int srow = 32 * wv + (lane >> 3);
  const int scol = ((lane & 7) ^ ((lane >> 3) & 7)) * 8;
  const unsigned short* aSrc = Ab + (size_t)(bm + srow) * K + scol;
  const unsigned short* bSrc = BT + (size_t)(bn + srow) * K + scol;
  const size_t rowK8 = (size_t)8 * K;

  f32x4 acc[8][4] = {};

  auto STAGE = [&](int b, int kt) {
    short* Asb = smem + b * 16384;
    short* Bsb = smem + 32768 + b * 16384;
#pragma unroll
    for (int i = 0; i < 4; i++) {
      gld16(aSrc + kt + i * rowK8, Asb + (wv * 4 + i) * 512);
      gld16(bSrc + kt + i * rowK8, Bsb + (wv * 4 + i) * 512);
    }
  };
  auto COMPUTE = [&](int b) {
    const short* Asb = smem + b * 16384;
    const short* Bsb = smem + 32768 + b * 16384;
#pragma unroll
    for (int kk = 0; kk < 2; kk++) {
      const int csw = 8 * ((4 * kk + lg) ^ (lc & 7));
      s16x8 bf[4];
#pragma unroll
      for (int c = 0; c < 4; c++)
        bf[c] = *(const s16x8*)&Bsb[(wc * 64 + c * 16 + lc) * 64 + csw];
#pragma unroll
      for (int r = 0; r < 8; r++) {
        s16x8 af = *(const s16x8*)&Asb[(wr * 128 + r * 16 + lc) * 64 + csw];
#pragma unroll
        for (int c = 0; c < 4; c++)
          acc[r][c] = __builtin_amdgcn_mfma_f32_16x16x32_bf16(af, bf[c], acc[r][c], 0, 0, 0);
      }
    }
  };

  STAGE(0, 0);
  int cur = 0;
  for (int kt = 64; kt < K; kt += 64) {
    STAGE(cur ^ 1, kt);                                // next tile in flight
    asm volatile("s_waitcnt vmcnt(8)" ::: "memory");   // prev tile retired
    __builtin_amdgcn_s_barrier();
    __builtin_amdgcn_sched_barrier(0);
    COMPUTE(cur);
    __builtin_amdgcn_s_barrier();                      // reads done before reuse
    cur ^= 1;
  }
  asm volatile("s_waitcnt vmcnt(0)" ::: "memory");
  __builtin_amdgcn_s_barrier();
  __builtin_amdgcn_sched_barrier(0);
  COMPUTE(cur);

#pragma unroll
  for (int r = 0; r < 8; r++) {
    const int rbase = bm + wr * 128 + r * 16 + lg * 4;
#pragma unroll
    for (int c = 0; c < 4; c++) {
      const int cg = bn + wc * 64 + c * 16 + lc;
#pragma unroll
      for (int rr = 0; rr < 4; rr++) {
        float val = acc[r][c][rr] + bias[cg];
        if (EPI == 2) ((float*)Cout)[(size_t)(rbase + rr) * N + cg] = val;
        else ((unsigned short*)Cout)[(size_t)(rbase + rr) * N + cg] = f2bf(val);
      }
    }
  }
}

// ---------------- LayerNorm, in place (wave per row) ----------------
__global__ __launch_bounds__(256) void ln_kernel(
    unsigned short* __restrict__ xa,
    const float* __restrict__ g_pt, const float* __restrict__ be_pt,
    const float* __restrict__ g_ps, const float* __restrict__ be_ps)
{
  const int row = blockIdx.x * 4 + (threadIdx.x >> 6);
  const int lane = threadIdx.x & 63;
  const bool isT = row < TROWS;
  const float* gg = isT ? g_pt : g_ps;
  const float* be = isT ? be_pt : be_ps;
  unsigned short* p = xa + (size_t)row * CDIM;
  const int c0 = lane * 8;

  s16x8 v8 = *(const s16x8*)&p[c0];
  float f[8];
  float s = 0.f, s2 = 0.f;
#pragma unroll
  for (int i = 0; i < 8; i++) {
    float xv = bf2f((unsigned short)v8[i]);
    f[i] = xv; s += xv; s2 += xv * xv;
  }
#pragma unroll
  for (int d = 1; d < 64; d <<= 1) { s += __shfl_xor(s, d); s2 += __shfl_xor(s2, d); }
  float mu = s * (1.f / CDIM);
  float var = s2 * (1.f / CDIM) - mu * mu;
  float rs = rsqrtf(var + 1e-5f);

  float4 g0 = *(const float4*)&gg[c0], g1 = *(const float4*)&gg[c0 + 4];
  float4 e0 = *(const float4*)&be[c0], e1 = *(const float4*)&be[c0 + 4];
  float gv[8] = {g0.x, g0.y, g0.z, g0.w, g1.x, g1.y, g1.z, g1.w};
  float ev[8] = {e0.x, e0.y, e0.z, e0.w, e1.x, e1.y, e1.z, e1.w};
  s16x8 o;
#pragma unroll
  for (int i = 0; i < 8; i++)
    o[i] = (short)f2bf((f[i] - mu) * rs * gv[i] + ev[i]);
  *(s16x8*)&p[c0] = o;
}

// ---------------- fused attention (unchanged from r16) ----------------
__global__ __launch_bounds__(576) void attn_kernel(
    const unsigned short* __restrict__ qkv, const unsigned short* __restrict__ cmb,
    unsigned short* __restrict__ outp)
{
  __shared__ short VT[32 * 168];
  const int nb = NWIN * NHEADS;
  const int lid = (blockIdx.x & 7) * (nb >> 3) + (blockIdx.x >> 3);
  const int w = lid >> 4, h = lid & 15;
  const int t = threadIdx.x;
  const unsigned short* qb = qkv + (size_t)w * NTOK * 1536;
  const int hq = h * 32;

  {
    const int n = t >> 2, d0 = (t & 3) * 8;
    s16x8 vv = *(const s16x8*)&qb[(size_t)n * 1536 + 1024 + hq + d0];
#pragma unroll
    for (int i = 0; i < 8; i++) VT[(d0 + i) * 168 + n] = vv[i];
  }
  if (t < 512) VT[(t >> 4) * 168 + 144 + (t & 15)] = 0;

  const int lane = t & 63, wv = t >> 6, lg = lane >> 4, lc = lane & 15;
  const int q = wv * 16 + lc;
  const f32x4 zero = {0.f, 0.f, 0.f, 0.f};

  const s16x8 qf = *(const s16x8*)&qb[(size_t)q * 1536 + hq + lg * 8];

  const int cls = (w < 64) ? (w & 3) : 4 + ((w - 64) & 15);
  const unsigned short* cm =
      cmb + ((size_t)cls * NHEADS + h) * (NTOK * NTOK) + (size_t)q * NTOK;
  uint2 cmr[9];
#pragma unroll
  for (int nt = 0; nt < 9; nt++)
    cmr[nt] = *(const uint2*)&cm[nt * 16 + lg * 4];

  f32x4 accS[9];
  __builtin_amdgcn_s_setprio(1);
#pragma unroll
  for (int nt = 0; nt < 9; nt++) {
    s16x8 kf = *(const s16x8*)&qb[(size_t)(nt * 16 + lc) * 1536 + 512 + hq + lg * 8];
    accS[nt] = __builtin_amdgcn_mfma_f32_16x16x32_bf16(kf, qf, zero, 0, 0, 0);
  }
  __builtin_amdgcn_s_setprio(0);

  float mx = -1e30f;
#pragma unroll
  for (int nt = 0; nt < 9; nt++) {
    accS[nt][0] += bf2f((unsigned short)(cmr[nt].x & 0xffff));
    accS[nt][1] += bf2f((unsigned short)(cmr[nt].x >> 16));
    accS[nt][2] += bf2f((unsigned short)(cmr[nt].y & 0xffff));
    accS[nt][3] += bf2f((unsigned short)(cmr[nt].y >> 16));
#pragma unroll
    for (int r = 0; r < 4; r++) mx = fmaxf(mx, accS[nt][r]);
  }
  mx = fmaxf(mx, __shfl_xor(mx, 16));
  mx = fmaxf(mx, __shfl_xor(mx, 32));

  float sum = 0.f;
#pragma unroll
  for (int nt = 0; nt < 9; nt++)
#pragma unroll
    for (int r = 0; r < 4; r++) {
      float e = __expf(accS[nt][r] - mx);
      accS[nt][r] = e;
      sum += e;
    }
  sum += __shfl_xor(sum, 16);
  sum += __shfl_xor(sum, 32);
  const float inv = 1.f / sum;

  unsigned pk0[9], pk1[9];
#pragma unroll
  for (int nt = 0; nt < 9; nt++) {
    pk0[nt] = (unsigned)f2bf(accS[nt][0]) | ((unsigned)f2bf(accS[nt][1]) << 16);
    pk1[nt] = (unsigned)f2bf(accS[nt][2]) | ((unsigned)f2bf(accS[nt][3]) << 16);
  }

  __syncthreads();

  __builtin_amdgcn_s_setprio(1);
#pragma unroll
  for (int dt = 0; dt < 2; dt++) {
    const short* vbase = &VT[(dt * 16 + lc) * 168];
    f32x4 accO = zero;
#pragma unroll
    for (int kk = 0; kk < 4; kk++) {
      u32x2 A0 = *(const u32x2*)&vbase[32 * kk + lg * 4];
      u32x2 A1 = *(const u32x2*)&vbase[32 * kk + 16 + lg * 4];
      s16x8 a = mk8(A0[0], A0[1], A1[0], A1[1]);
      s16x8 b = mk8(pk0[2 * kk], pk1[2 * kk], pk0[2 * kk + 1], pk1[2 * kk + 1]);
      accO = __builtin_amdgcn_mfma_f32_16x16x32_bf16(a, b, accO, 0, 0, 0);
    }
    {
      u32x2 A0 = *(const u32x2*)&vbase[128 + lg * 4];
      s16x8 a = mk8(A0[0], A0[1], 0u, 0u);
      s16x8 b = mk8(pk0[8], pk1[8], 0u, 0u);
      accO = __builtin_amdgcn_mfma_f32_16x16x32_bf16(a, b, accO, 0, 0, 0);
    }
    unsigned o0 = (unsigned)f2bf(accO[0] * inv) | ((unsigned)f2bf(accO[1] * inv) << 16);
    unsigned o1 = (unsigned)f2bf(accO[2] * inv) | ((unsigned)f2bf(accO[3] * inv) << 16);
    uint2 st; st.x = o0; st.y = o1;
    *(uint2*)&outp[(size_t)(w * NTOK + q) * CDIM + hq + dt * 16 + lg * 4] = st;
  }
  __builtin_amdgcn_s_setprio(0);
}

// ---------------- launch ----------------
extern "C" void kernel_launch(void* const* d_in, const int* in_sizes, int n_in,
                              void* d_out, int out_size, void* d_ws, size_t ws_size,
                              hipStream_t stream)
{
  const float* x     = (const float*)d_in[0];
  const float* tpl   = (const float*)d_in[1];
  const float* mask0 = (const float*)d_in[2];
  const float* mask1 = (const float*)d_in[3];
  const float* rpb   = (const float*)d_in[8];
  const float* w_ps  = (const float*)d_in[9];
  const float* b_ps  = (const float*)d_in[10];
  const float* g_ps  = (const float*)d_in[11];
  const float* be_ps = (const float*)d_in[12];
  const float* w_pt  = (const float*)d_in[13];
  const float* b_pt  = (const float*)d_in[14];
  const float* g_pt  = (const float*)d_in[15];
  const float* be_pt = (const float*)d_in[16];
  const float* w_qkv = (const float*)d_in[17];
  const float* b_qkv = (const float*)d_in[18];
  const float* w_tr  = (const float*)d_in[19];
  const float* b_tr  = (const float*)d_in[20];
  const float* w_sr  = (const float*)d_in[21];
  const float* b_sr  = (const float*)d_in[22];

  char* ws = (char*)d_ws;
  unsigned short* wpsT  = (unsigned short*)(ws + 0x0000000);
  unsigned short* wptT  = (unsigned short*)(ws + 0x0100000);
  unsigned short* wqkvT = (unsigned short*)(ws + 0x0200000);
  unsigned short* wtrT  = (unsigned short*)(ws + 0x0380000);
  unsigned short* wsrT  = (unsigned short*)(ws + 0x0480000);
  unsigned short* cmb   = (unsigned short*)(ws + 0x0580000);
  float* bqS            = (float*)(ws + 0x12F0000);
  unsigned short* xa    = (unsigned short*)(ws + 0x1300000);
  unsigned short* Sa    = (unsigned short*)(ws + 0x4000000);   // cast-A (union w/ qkv)
  unsigned short* qkvF  = (unsigned short*)(ws + 0x4000000);
  float* outb           = (float*)d_out;

  // allow 128KB dynamic LDS (idempotent; not a stream op)
  hipFuncSetAttribute((const void*)gemm256<0>,
                      hipFuncAttributeMaxDynamicSharedMemorySize, 131072);
  hipFuncSetAttribute((const void*)gemm256<2>,
                      hipFuncAttributeMaxDynamicSharedMemorySize, 131072);

  transpose_cast<<<2048, 256, 0, stream>>>(w_ps, wpsT, 1024, 512, 0, 1.f);
  transpose_cast<<<2048, 256, 0, stream>>>(w_pt, wptT, 1024, 512, 0, 1.f);
  transpose_cast<<<3072, 256, 0, stream>>>(w_qkv, wqkvT, 512, 1536,
                                           512, 0.17677669529663687f);
  transpose_cast<<<2048, 256, 0, stream>>>(w_tr, wtrT, 512, 1024, 0, 1.f);
  transpose_cast<<<2048, 256, 0, stream>>>(w_sr, wsrT, 512, 1024, 0, 1.f);
  scale_bias<<<6, 256, 0, stream>>>(b_qkv, bqS);
  build_cmb<<<(NCLS * NHEADS * NTOK * NTOK + 255) / 256, 256, 0, stream>>>(rpb, mask0, mask1, cmb);

  // cast inputs to bf16: tpl -> Sa[0:9216), x -> Sa[9216:46080)
  cast_bf16<<<(TROWS * 1024 / 8 + 255) / 256, 256, 0, stream>>>(tpl, Sa, TROWS * 1024 / 8);
  cast_bf16<<<(SROWS * 1024 / 8 + 255) / 256, 256, 0, stream>>>(
      x, Sa + (size_t)TROWS * 1024, SROWS * 1024 / 8);

  // projection GEMM -> xa bf16
  gemm256<0><<<dim3(2, 180), 512, 131072, stream>>>(Sa, wptT, wpsT, b_pt, b_ps,
                                                    xa, TOTROWS, CDIM, 1024);
  // LayerNorm in place on xa
  ln_kernel<<<TOTROWS / 4, 256, 0, stream>>>(xa, g_pt, be_pt, g_ps, be_ps);

  // QKV GEMM (Q-scale folded) -> qkvF (overwrites dead Sa)
  gemm256<0><<<dim3(6, 180), 512, 131072, stream>>>(xa, wqkvT, wqkvT, bqS, bqS,
                                                    qkvF, TOTROWS, 1536, CDIM);
  // fused attention -> xa
  attn_kernel<<<NWIN * NHEADS, 576, 0, stream>>>(qkvF, cmb, xa);

  // output GEMM -> d_out f32
  gemm256<2><<<dim3(4, 180), 512, 131072, stream>>>(xa, wtrT, wsrT, b_tr, b_sr,
                                                    outb, TOTROWS, 1024, CDIM);
}